// Round 11
// baseline (180.501 us; speedup 1.0000x reference)
//
#include <hip/hip_runtime.h>

#define GRIDSZ 64
#define NBATCH 16
#define NPTS   500000
#define NTRIP  (NPTS / 4)          // 125000 triples-of-float4 (4 points each)
#define FLOATS_PER_BATCH (NPTS * 3)
#define BINS_PER_BATCH (GRIDSZ * GRIDSZ * GRIDSZ)   // 262144

// fused kernel geometry
#define CHUNKS   32                 // blocks per batch
#define FBLOCKS  (NBATCH * CHUNKS)  // 512 blocks == 2/CU guaranteed resident
#define FTHREADS 512
#define R0  16                      // central region = bins [16,48) per dim
#define RSZ 32
#define WORDS8 (RSZ * RSZ * (RSZ / 4))  // 8192 u32 words (4 u8 counts) = 32KB

// fallback minmax config
#define MMBLK 128

// ws layout (u32 units):
//  [0..15]    arrive1[16]   (per-batch barrier A)
//  [16..31]   arrive2[16]   (per-batch barrier C)
//  [128..255] finals (fallback path)
//  [256..16639]  mm partials (fallback needs 2048*8; fused uses 512*8)
//  [16640.. ]    hist u8 partials: FBLOCKS x WORDS8 u32 = 16 MB
#define ARR1_OFF 0
#define ARR2_OFF 16
#define FINAL_OFF 128
#define MMPART_OFF 256
#define HPART_OFF (MMPART_OFF + 2048 * 8)   // 16640

__global__ void init_counters(unsigned* __restrict__ ws) {
    if (threadIdx.x < 32) ws[threadIdx.x] = 0u;   // arrive1 + arrive2
}

// Per-batch soft barrier: 32 co-resident blocks. Release via threadfence
// before the arrive add; acquire via threadfence after the spin.
__device__ __forceinline__ void batch_barrier(unsigned* cnt) {
    __syncthreads();
    if (threadIdx.x == 0) {
        __threadfence();
        atomicAdd(cnt, 1u);
        while (atomicAdd(cnt, 0u) < (unsigned)CHUNKS) {
            __builtin_amdgcn_s_sleep(16);
        }
        __threadfence();
    }
    __syncthreads();
}

// Shared binning math — EXACTLY the arithmetic of the passing rounds.
__device__ __forceinline__ void bin_point(float x, float y, float z,
                                          float mn0, float mn1, float mn2,
                                          float d0, float d1, float d2,
                                          bool& ok, int& ix, int& iy, int& iz) {
    float tx = (x - mn0) / d0;
    float ty = (y - mn1) / d1;
    float tz = (z - mn2) / d2;
    float nx = tx * 2.0f - 1.0f;
    float ny = ty * 2.0f - 1.0f;
    float nz = tz * 2.0f - 1.0f;
    ok = (nx >= -1.0f) & (nx <= 1.0f) &
         (ny >= -1.0f) & (ny <= 1.0f) &
         (nz >= -1.0f) & (nz <= 1.0f);
    ix = (int)floorf((nx + 1.0f) * 32.0f);
    iy = (int)floorf((ny + 1.0f) * 32.0f);
    iz = (int)floorf((nz + 1.0f) * 32.0f);
    ix = min(max(ix, 0), GRIDSZ - 1);
    iy = min(max(iy, 0), GRIDSZ - 1);
    iz = min(max(iz, 0), GRIDSZ - 1);
}

// ONE kernel: zero-out + minmax -> barrier -> hist -> barrier -> reduce.
// Per-batch barriers let the 16 batches pipeline phases independently.
__global__ __launch_bounds__(FTHREADS, 4) void fused_kernel(
        const float* __restrict__ pts,
        float* __restrict__ mm_partials,
        unsigned* __restrict__ hist_partials,
        unsigned* __restrict__ arrive1,
        unsigned* __restrict__ arrive2,
        float* __restrict__ out) {
    __shared__ unsigned cnt[WORDS8];     // 32 KB
    __shared__ float red[8][6];
    __shared__ float fin[6];

    const int bx = blockIdx.x;
    const int b = bx >> 5;
    const int chunk = bx & (CHUNKS - 1);
    const int tid = threadIdx.x;

    for (int w = tid; w < WORDS8; w += FTHREADS) cnt[w] = 0u;

    // ---- Phase A: zero own batch's output slice + chunk min/max ----
    {
        float4* outb4 = reinterpret_cast<float4*>(out + (size_t)b * BINS_PER_BATCH);
        const float4 z = make_float4(0.f, 0.f, 0.f, 0.f);
        const int base = chunk * 2048 + tid;   // 65536 float4/batch, 2048/chunk
#pragma unroll
        for (int k = 0; k < 4; ++k) outb4[base + k * FTHREADS] = z;
    }

    const float4* __restrict__ p4 =
        reinterpret_cast<const float4*>(pts + (size_t)b * FLOATS_PER_BATCH);

    float mn[3] = {INFINITY, INFINITY, INFINITY};
    float mx[3] = {-INFINITY, -INFINITY, -INFINITY};
    for (int i = chunk * FTHREADS + tid; i < NTRIP; i += CHUNKS * FTHREADS) {
        float4 A = p4[3 * i + 0];
        float4 B = p4[3 * i + 1];
        float4 C = p4[3 * i + 2];
        // 4 points: (A.x,A.y,A.z) (A.w,B.x,B.y) (B.z,B.w,C.x) (C.y,C.z,C.w)
        float xs[4] = {A.x, A.w, B.z, C.y};
        float ys[4] = {A.y, B.x, B.w, C.z};
        float zs[4] = {A.z, B.y, C.x, C.w};
#pragma unroll
        for (int j = 0; j < 4; ++j) {
            mn[0] = fminf(mn[0], xs[j]); mx[0] = fmaxf(mx[0], xs[j]);
            mn[1] = fminf(mn[1], ys[j]); mx[1] = fmaxf(mx[1], ys[j]);
            mn[2] = fminf(mn[2], zs[j]); mx[2] = fmaxf(mx[2], zs[j]);
        }
    }
#pragma unroll
    for (int m = 1; m < 64; m <<= 1) {
#pragma unroll
        for (int c = 0; c < 3; ++c) {
            mn[c] = fminf(mn[c], __shfl_xor(mn[c], m));
            mx[c] = fmaxf(mx[c], __shfl_xor(mx[c], m));
        }
    }
    const int wave = tid >> 6;
    if ((tid & 63) == 0) {
        red[wave][0] = mn[0]; red[wave][1] = mn[1]; red[wave][2] = mn[2];
        red[wave][3] = mx[0]; red[wave][4] = mx[1]; red[wave][5] = mx[2];
    }
    __syncthreads();
    if (tid == 0) {
#pragma unroll
        for (int w = 1; w < 8; ++w) {
#pragma unroll
            for (int c = 0; c < 3; ++c) {
                red[0][c]     = fminf(red[0][c],     red[w][c]);
                red[0][3 + c] = fmaxf(red[0][3 + c], red[w][3 + c]);
            }
        }
        float4* slot = reinterpret_cast<float4*>(mm_partials + (size_t)bx * 8);
        slot[0] = make_float4(red[0][0], red[0][1], red[0][2], red[0][3]);
        slot[1] = make_float4(red[0][4], red[0][5], 0.0f, 0.0f);
    }

    batch_barrier(&arrive1[b]);   // batch b fully min/max'd + zeroed

    // ---- Phase B: finalize mn/den (order-invariant, bit-identical), hist ----
    if (tid < CHUNKS) {
        const float4* slot = reinterpret_cast<const float4*>(
            mm_partials + (size_t)(b * CHUNKS + tid) * 8);
        float4 a = slot[0];
        float4 c = slot[1];
        float pmn[3] = {a.x, a.y, a.z};
        float pmx[3] = {a.w, c.x, c.y};
#pragma unroll
        for (int m = 1; m < 32; m <<= 1) {
#pragma unroll
            for (int k = 0; k < 3; ++k) {
                pmn[k] = fminf(pmn[k], __shfl_xor(pmn[k], m));
                pmx[k] = fmaxf(pmx[k], __shfl_xor(pmx[k], m));
            }
        }
        if (tid == 0) {
#pragma unroll
            for (int k = 0; k < 3; ++k) {
                fin[k]     = pmn[k];
                fin[3 + k] = (pmx[k] - pmn[k]) + 1e-6f;   // ref: (pmax-pmin)+EPS
            }
        }
    }
    __syncthreads();

    const float mn0 = fin[0], mn1 = fin[1], mn2 = fin[2];
    const float d0 = fin[3], d1 = fin[4], d2 = fin[5];
    float* __restrict__ outb = out + (size_t)b * BINS_PER_BATCH;

    for (int i = chunk * FTHREADS + tid; i < NTRIP; i += CHUNKS * FTHREADS) {
        float4 A = p4[3 * i + 0];
        float4 B = p4[3 * i + 1];
        float4 C = p4[3 * i + 2];
        float xs[4] = {A.x, A.w, B.z, C.y};
        float ys[4] = {A.y, B.x, B.w, C.z};
        float zs[4] = {A.z, B.y, C.x, C.w};
#pragma unroll
        for (int j = 0; j < 4; ++j) {
            bool ok; int ix, iy, iz;
            bin_point(xs[j], ys[j], zs[j], mn0, mn1, mn2, d0, d1, d2, ok, ix, iy, iz);
            if (ok) {
                unsigned rx = (unsigned)(ix - R0), ry = (unsigned)(iy - R0), rz = (unsigned)(iz - R0);
                if ((rx < RSZ) & (ry < RSZ) & (rz < RSZ)) {
                    unsigned word = (rx * RSZ + ry) * (RSZ / 4) + (rz >> 2);
                    atomicAdd(&cnt[word], 1u << ((rz & 3u) * 8u));
                } else {
                    int bin = (ix * GRIDSZ + iy) * GRIDSZ + iz;
                    atomicAdd(&outb[bin], 1.0f);   // zeros visible via barrier1
                }
            }
        }
    }
    __syncthreads();

    // ---- Phase C: flush partials, barrier, per-slice reduce + store ----
    {
        unsigned* __restrict__ slot = hist_partials + (size_t)bx * WORDS8;
        for (int w = tid; w < WORDS8; w += FTHREADS) slot[w] = cnt[w];
    }

    batch_barrier(&arrive2[b]);   // batch b's partials all flushed

    if (tid < 256) {
        const int w = chunk * 256 + tid;                 // rx == chunk
        const unsigned* __restrict__ base =
            hist_partials + (size_t)b * CHUNKS * WORDS8;
        unsigned s0 = 0, s1 = 0, s2 = 0, s3 = 0;
#pragma unroll 4
        for (int c = 0; c < CHUNKS; ++c) {
            unsigned v = base[(size_t)c * WORDS8 + w];
            s0 += v & 0xFFu;
            s1 += (v >> 8) & 0xFFu;
            s2 += (v >> 16) & 0xFFu;
            s3 += v >> 24;
        }
        int ry = (w >> 3) & (RSZ - 1);
        int rz = (w & (RSZ / 4 - 1)) << 2;
        int bin = ((R0 + chunk) * GRIDSZ + (R0 + ry)) * GRIDSZ + (R0 + rz);
        *reinterpret_cast<float4*>(&outb[bin]) =
            make_float4((float)s0, (float)s1, (float)s2, (float)s3);
    }
}

// ---------- fallback path (ws too small): round-9 structure ----------
__global__ __launch_bounds__(256) void minmax_stage1(
        const float* __restrict__ pts, float* __restrict__ partials,
        float4* __restrict__ out4) {
    const int b = blockIdx.y;
    const int linBlk = b * MMBLK + blockIdx.x;
    const int linTid = linBlk * 256 + threadIdx.x;
    const float4 z = make_float4(0.f, 0.f, 0.f, 0.f);
    out4[linTid] = z;
    out4[linTid + MMBLK * NBATCH * 256] = z;

    const float4* __restrict__ p4 =
        reinterpret_cast<const float4*>(pts + (size_t)b * FLOATS_PER_BATCH);
    float mn[3] = {INFINITY, INFINITY, INFINITY};
    float mx[3] = {-INFINITY, -INFINITY, -INFINITY};
    const int stride = MMBLK * 256;
    for (int i = blockIdx.x * 256 + threadIdx.x; i < NTRIP; i += stride) {
        float4 A = p4[3 * i + 0];
        float4 B = p4[3 * i + 1];
        float4 C = p4[3 * i + 2];
        float xs[4] = {A.x, A.w, B.z, C.y};
        float ys[4] = {A.y, B.x, B.w, C.z};
        float zs[4] = {A.z, B.y, C.x, C.w};
#pragma unroll
        for (int j = 0; j < 4; ++j) {
            mn[0] = fminf(mn[0], xs[j]); mx[0] = fmaxf(mx[0], xs[j]);
            mn[1] = fminf(mn[1], ys[j]); mx[1] = fmaxf(mx[1], ys[j]);
            mn[2] = fminf(mn[2], zs[j]); mx[2] = fmaxf(mx[2], zs[j]);
        }
    }
#pragma unroll
    for (int m = 1; m < 64; m <<= 1) {
#pragma unroll
        for (int c = 0; c < 3; ++c) {
            mn[c] = fminf(mn[c], __shfl_xor(mn[c], m));
            mx[c] = fmaxf(mx[c], __shfl_xor(mx[c], m));
        }
    }
    __shared__ float red[4][6];
    const int wave = threadIdx.x >> 6;
    if ((threadIdx.x & 63) == 0) {
        red[wave][0] = mn[0]; red[wave][1] = mn[1]; red[wave][2] = mn[2];
        red[wave][3] = mx[0]; red[wave][4] = mx[1]; red[wave][5] = mx[2];
    }
    __syncthreads();
    if (threadIdx.x == 0) {
#pragma unroll
        for (int w = 1; w < 4; ++w) {
#pragma unroll
            for (int c = 0; c < 3; ++c) {
                red[0][c]     = fminf(red[0][c],     red[w][c]);
                red[0][3 + c] = fmaxf(red[0][3 + c], red[w][3 + c]);
            }
        }
        float4* slot = reinterpret_cast<float4*>(partials + (size_t)linBlk * 8);
        slot[0] = make_float4(red[0][0], red[0][1], red[0][2], red[0][3]);
        slot[1] = make_float4(red[0][4], red[0][5], 0.0f, 0.0f);
    }
}

__global__ __launch_bounds__(MMBLK) void minmax_stage2(
        const float* __restrict__ partials, float* __restrict__ finals) {
    const int b = blockIdx.x;
    const float4* slot = reinterpret_cast<const float4*>(
        partials + (size_t)(b * MMBLK + threadIdx.x) * 8);
    float4 a = slot[0];
    float4 c = slot[1];
    float mn[3] = {a.x, a.y, a.z};
    float mx[3] = {a.w, c.x, c.y};
#pragma unroll
    for (int m = 1; m < 64; m <<= 1) {
#pragma unroll
        for (int k = 0; k < 3; ++k) {
            mn[k] = fminf(mn[k], __shfl_xor(mn[k], m));
            mx[k] = fmaxf(mx[k], __shfl_xor(mx[k], m));
        }
    }
    __shared__ float red[2][6];
    const int wave = threadIdx.x >> 6;
    if ((threadIdx.x & 63) == 0) {
        red[wave][0] = mn[0]; red[wave][1] = mn[1]; red[wave][2] = mn[2];
        red[wave][3] = mx[0]; red[wave][4] = mx[1]; red[wave][5] = mx[2];
    }
    __syncthreads();
    if (threadIdx.x == 0) {
        float* f = finals + b * 8;
#pragma unroll
        for (int k = 0; k < 3; ++k) {
            float lo = fminf(red[0][k],     red[1][k]);
            float hi = fmaxf(red[0][3 + k], red[1][3 + k]);
            f[k]     = lo;
            f[3 + k] = (hi - lo) + 1e-6f;
        }
        f[6] = 0.0f; f[7] = 0.0f;
    }
}

__global__ void hist_kernel(const float* __restrict__ pts,
                            const float* __restrict__ finals,
                            float* __restrict__ out) {
    const int b = blockIdx.y;
    const float mn0 = finals[b * 8 + 0], mn1 = finals[b * 8 + 1], mn2 = finals[b * 8 + 2];
    const float d0  = finals[b * 8 + 3], d1  = finals[b * 8 + 4], d2  = finals[b * 8 + 5];
    const float4* __restrict__ p4 =
        reinterpret_cast<const float4*>(pts + (size_t)b * FLOATS_PER_BATCH);
    float* __restrict__ outb = out + (size_t)b * BINS_PER_BATCH;
    const int stride = gridDim.x * blockDim.x;
    for (int i = blockIdx.x * blockDim.x + threadIdx.x; i < NTRIP; i += stride) {
        float4 A = p4[3 * i + 0];
        float4 B = p4[3 * i + 1];
        float4 C = p4[3 * i + 2];
        float xs[4] = {A.x, A.w, B.z, C.y};
        float ys[4] = {A.y, B.x, B.w, C.z};
        float zs[4] = {A.z, B.y, C.x, C.w};
#pragma unroll
        for (int j = 0; j < 4; ++j) {
            bool ok; int ix, iy, iz;
            bin_point(xs[j], ys[j], zs[j], mn0, mn1, mn2, d0, d1, d2, ok, ix, iy, iz);
            if (ok) {
                int bin = (ix * GRIDSZ + iy) * GRIDSZ + iz;
                atomicAdd(&outb[bin], 1.0f);
            }
        }
    }
}

extern "C" void kernel_launch(void* const* d_in, const int* in_sizes, int n_in,
                              void* d_out, int out_size, void* d_ws, size_t ws_size,
                              hipStream_t stream) {
    const float* pts = (const float*)d_in[0];
    float* out = (float*)d_out;
    unsigned* ws = (unsigned*)d_ws;

    float* finals = (float*)(ws + FINAL_OFF);
    float* mm_partials = (float*)(ws + MMPART_OFF);
    unsigned* hist_partials = ws + HPART_OFF;

    const size_t need = ((size_t)HPART_OFF + (size_t)FBLOCKS * WORDS8) * 4;

    if (ws_size >= need) {
        init_counters<<<1, 64, 0, stream>>>(ws);
        fused_kernel<<<FBLOCKS, FTHREADS, 0, stream>>>(
            pts, mm_partials, hist_partials,
            ws + ARR1_OFF, ws + ARR2_OFF, out);
    } else {
        minmax_stage1<<<dim3(MMBLK, NBATCH), 256, 0, stream>>>(
            pts, mm_partials, (float4*)out);
        minmax_stage2<<<NBATCH, MMBLK, 0, stream>>>(mm_partials, finals);
        hist_kernel<<<dim3(128, NBATCH), 256, 0, stream>>>(pts, finals, out);
    }
}

// Round 12
// 68.339 us; speedup vs baseline: 2.6413x; 2.6413x over previous
//
#include <hip/hip_runtime.h>

#define GRIDSZ 64
#define NBATCH 16
#define NPTS   500000
#define NTRIP  (NPTS / 4)          // 125000 triples-of-float4 (4 points each)
#define FLOATS_PER_BATCH (NPTS * 3)
#define BINS_PER_BATCH (GRIDSZ * GRIDSZ * GRIDSZ)

// LDS-privatized histogram parameters (u8-packed: 4 counts per u32)
#define CHUNKS   64                 // blocks per batch in hist pass (r12: 32->64, 4 blocks/CU)
#define HBLOCKS  (NBATCH * CHUNKS)  // 1024 blocks
#define HTHREADS 512
#define R0  16                      // central region = bins [16,48) per dim
#define RSZ 32
#define WORDS8 (RSZ * RSZ * (RSZ / 4))  // 8192 u32 words (4 u8 counts each) = 32KB

// minmax config
#define MMBLK 128                   // stage-1 blocks per batch
#define MMTOTTHREADS (MMBLK * NBATCH * 256)   // 524288

// ws layout (u32 units):
//  [0 .. 127]     finals (fallback path only): per batch 8 floats
//  [128 .. 255]   pad
//  [256 .. 16639] mm stage-1 partials: 2048 blocks x 8 floats = 64KB
//  [16640 .. ]    hist u8 partials: HBLOCKS x WORDS8 u32 = 32MB (round-3 layout
//                 needed 33.6MB and ran, so ws_size accommodates this)
#define FINAL_OFF 0
#define PART_OFF_U32 256
#define HIST_PART_OFF_U32 (PART_OFF_U32 + MMBLK * NBATCH * 8)   // 16640

// Stage 1 also zeroes d_out (runtime fillBufferAligned was ~300 GB/s for
// 16 MB — round-7 profile). Stream ordering makes zeros visible to hist.
__global__ __launch_bounds__(256) void minmax_stage1(
        const float* __restrict__ pts, float* __restrict__ partials,
        float4* __restrict__ out4) {
    const int b = blockIdx.y;
    const int linBlk = b * MMBLK + blockIdx.x;          // 0..2047
    const int linTid = linBlk * 256 + threadIdx.x;      // 0..524287

    const float4 z = make_float4(0.f, 0.f, 0.f, 0.f);
    out4[linTid] = z;
    out4[linTid + MMTOTTHREADS] = z;

    const float4* __restrict__ p4 =
        reinterpret_cast<const float4*>(pts + (size_t)b * FLOATS_PER_BATCH);

    float mn[3] = {INFINITY, INFINITY, INFINITY};
    float mx[3] = {-INFINITY, -INFINITY, -INFINITY};

    const int stride = MMBLK * 256;
    for (int i = blockIdx.x * 256 + threadIdx.x; i < NTRIP; i += stride) {
        float4 A = p4[3 * i + 0];
        float4 B = p4[3 * i + 1];
        float4 C = p4[3 * i + 2];
        // 4 points: (A.x,A.y,A.z) (A.w,B.x,B.y) (B.z,B.w,C.x) (C.y,C.z,C.w)
        float xs[4] = {A.x, A.w, B.z, C.y};
        float ys[4] = {A.y, B.x, B.w, C.z};
        float zs[4] = {A.z, B.y, C.x, C.w};
#pragma unroll
        for (int j = 0; j < 4; ++j) {
            mn[0] = fminf(mn[0], xs[j]); mx[0] = fmaxf(mx[0], xs[j]);
            mn[1] = fminf(mn[1], ys[j]); mx[1] = fmaxf(mx[1], ys[j]);
            mn[2] = fminf(mn[2], zs[j]); mx[2] = fmaxf(mx[2], zs[j]);
        }
    }
#pragma unroll
    for (int m = 1; m < 64; m <<= 1) {
#pragma unroll
        for (int c = 0; c < 3; ++c) {
            mn[c] = fminf(mn[c], __shfl_xor(mn[c], m));
            mx[c] = fmaxf(mx[c], __shfl_xor(mx[c], m));
        }
    }
    __shared__ float red[4][6];
    const int wave = threadIdx.x >> 6;
    if ((threadIdx.x & 63) == 0) {
        red[wave][0] = mn[0]; red[wave][1] = mn[1]; red[wave][2] = mn[2];
        red[wave][3] = mx[0]; red[wave][4] = mx[1]; red[wave][5] = mx[2];
    }
    __syncthreads();
    if (threadIdx.x == 0) {
#pragma unroll
        for (int w = 1; w < 4; ++w) {
#pragma unroll
            for (int c = 0; c < 3; ++c) {
                red[0][c]     = fminf(red[0][c],     red[w][c]);
                red[0][3 + c] = fmaxf(red[0][3 + c], red[w][3 + c]);
            }
        }
        float4* slot = reinterpret_cast<float4*>(partials + (size_t)linBlk * 8);
        slot[0] = make_float4(red[0][0], red[0][1], red[0][2], red[0][3]);
        slot[1] = make_float4(red[0][4], red[0][5], 0.0f, 0.0f);
    }
}

// Fallback-path only: reduce MMBLK partials -> finals {mn[3], den[3]}
__global__ __launch_bounds__(MMBLK) void minmax_stage2(
        const float* __restrict__ partials, float* __restrict__ finals) {
    const int b = blockIdx.x;
    const float4* slot = reinterpret_cast<const float4*>(
        partials + (size_t)(b * MMBLK + threadIdx.x) * 8);
    float4 a = slot[0];
    float4 c = slot[1];
    float mn[3] = {a.x, a.y, a.z};
    float mx[3] = {a.w, c.x, c.y};
#pragma unroll
    for (int m = 1; m < 64; m <<= 1) {
#pragma unroll
        for (int k = 0; k < 3; ++k) {
            mn[k] = fminf(mn[k], __shfl_xor(mn[k], m));
            mx[k] = fmaxf(mx[k], __shfl_xor(mx[k], m));
        }
    }
    __shared__ float red[2][6];
    const int wave = threadIdx.x >> 6;
    if ((threadIdx.x & 63) == 0) {
        red[wave][0] = mn[0]; red[wave][1] = mn[1]; red[wave][2] = mn[2];
        red[wave][3] = mx[0]; red[wave][4] = mx[1]; red[wave][5] = mx[2];
    }
    __syncthreads();
    if (threadIdx.x == 0) {
        float* f = finals + b * 8;
#pragma unroll
        for (int k = 0; k < 3; ++k) {
            float lo = fminf(red[0][k],     red[1][k]);
            float hi = fmaxf(red[0][3 + k], red[1][3 + k]);
            f[k]     = lo;
            f[3 + k] = (hi - lo) + 1e-6f;   // matches ref: (pmax-pmin)+EPS
        }
        f[6] = 0.0f; f[7] = 0.0f;
    }
}

// Shared binning math — EXACTLY the arithmetic of the passing rounds.
__device__ __forceinline__ void bin_point(float x, float y, float z,
                                          float mn0, float mn1, float mn2,
                                          float d0, float d1, float d2,
                                          bool& ok, int& ix, int& iy, int& iz) {
    float tx = (x - mn0) / d0;
    float ty = (y - mn1) / d1;
    float tz = (z - mn2) / d2;
    float nx = tx * 2.0f - 1.0f;
    float ny = ty * 2.0f - 1.0f;
    float nz = tz * 2.0f - 1.0f;
    ok = (nx >= -1.0f) & (nx <= 1.0f) &
         (ny >= -1.0f) & (ny <= 1.0f) &
         (nz >= -1.0f) & (nz <= 1.0f);
    ix = (int)floorf((nx + 1.0f) * 32.0f);
    iy = (int)floorf((ny + 1.0f) * 32.0f);
    iz = (int)floorf((nz + 1.0f) * 32.0f);
    ix = min(max(ix, 0), GRIDSZ - 1);
    iy = min(max(iy, 0), GRIDSZ - 1);
    iz = min(max(iz, 0), GRIDSZ - 1);
}

// u8-packed LDS hist. Each block: (1) reduce the 128 mm-partials itself
// (fmin/fmax order-invariant => bit-identical mn/den), (2) count central 32^3
// bins in 32KB LDS (u8 x4 per word; per-chunk per-bin max ~12 vs 255 cap),
// (3) flush with plain stores. 32KB LDS -> 4 blocks/CU, 100% occupancy.
__global__ __launch_bounds__(HTHREADS) void hist_lds_kernel(
        const float* __restrict__ pts, const float* __restrict__ mm_partials,
        unsigned* __restrict__ partials, float* __restrict__ out) {
    __shared__ unsigned cnt[WORDS8];         // 32 KB
    __shared__ float fin[6];
    const int bx = blockIdx.x;
    const int b = bx >> 6;                   // batch (CHUNKS=64)
    const int chunk = bx & (CHUNKS - 1);

    for (int w = threadIdx.x; w < WORDS8; w += HTHREADS) cnt[w] = 0u;

    // per-block finals reduction (threads 0..127, 2 waves)
    if (threadIdx.x < MMBLK) {
        const float4* slot = reinterpret_cast<const float4*>(
            mm_partials + (size_t)(b * MMBLK + threadIdx.x) * 8);
        float4 a = slot[0];
        float4 c = slot[1];
        float mn[3] = {a.x, a.y, a.z};
        float mx[3] = {a.w, c.x, c.y};
#pragma unroll
        for (int m = 1; m < 64; m <<= 1) {
#pragma unroll
            for (int k = 0; k < 3; ++k) {
                mn[k] = fminf(mn[k], __shfl_xor(mn[k], m));
                mx[k] = fmaxf(mx[k], __shfl_xor(mx[k], m));
            }
        }
        __shared__ float red[2][6];
        const int wave = threadIdx.x >> 6;
        if ((threadIdx.x & 63) == 0) {
            red[wave][0] = mn[0]; red[wave][1] = mn[1]; red[wave][2] = mn[2];
            red[wave][3] = mx[0]; red[wave][4] = mx[1]; red[wave][5] = mx[2];
        }
        __syncthreads();
        if (threadIdx.x == 0) {
#pragma unroll
            for (int k = 0; k < 3; ++k) {
                float lo = fminf(red[0][k],     red[1][k]);
                float hi = fmaxf(red[0][3 + k], red[1][3 + k]);
                fin[k]     = lo;
                fin[3 + k] = (hi - lo) + 1e-6f;   // matches ref
            }
        }
    } else {
        __syncthreads();   // matching barrier for threads >= 128
    }
    __syncthreads();

    const float mn0 = fin[0], mn1 = fin[1], mn2 = fin[2];
    const float d0 = fin[3], d1 = fin[4], d2 = fin[5];

    const float4* __restrict__ p4 =
        reinterpret_cast<const float4*>(pts + (size_t)b * FLOATS_PER_BATCH);
    float* __restrict__ outb = out + (size_t)b * BINS_PER_BATCH;

    for (int i = chunk * HTHREADS + threadIdx.x; i < NTRIP; i += CHUNKS * HTHREADS) {
        float4 A = p4[3 * i + 0];
        float4 B = p4[3 * i + 1];
        float4 C = p4[3 * i + 2];
        float xs[4] = {A.x, A.w, B.z, C.y};
        float ys[4] = {A.y, B.x, B.w, C.z};
        float zs[4] = {A.z, B.y, C.x, C.w};
#pragma unroll
        for (int j = 0; j < 4; ++j) {
            bool ok; int ix, iy, iz;
            bin_point(xs[j], ys[j], zs[j], mn0, mn1, mn2, d0, d1, d2, ok, ix, iy, iz);
            if (ok) {
                unsigned rx = (unsigned)(ix - R0), ry = (unsigned)(iy - R0), rz = (unsigned)(iz - R0);
                if ((rx < RSZ) & (ry < RSZ) & (rz < RSZ)) {
                    unsigned word = (rx * RSZ + ry) * (RSZ / 4) + (rz >> 2);
                    atomicAdd(&cnt[word], 1u << ((rz & 3u) * 8u));
                } else {
                    int bin = (ix * GRIDSZ + iy) * GRIDSZ + iz;
                    atomicAdd(&outb[bin], 1.0f);
                }
            }
        }
    }
    __syncthreads();

    unsigned* __restrict__ slot = partials + (size_t)bx * WORDS8;
    for (int w = threadIdx.x; w < WORDS8; w += HTHREADS) slot[w] = cnt[w];
}

// Sum the 64 per-chunk u8 partials per batch; coalesced float4 stores
// (outliers never touch central bins; out zeroed by minmax_stage1).
__global__ void reduce_kernel(const unsigned* __restrict__ partials,
                              float* __restrict__ out) {
    const int b = blockIdx.y;
    const int w = blockIdx.x * 256 + threadIdx.x;   // [0, WORDS8)
    const unsigned* __restrict__ base = partials + (size_t)b * CHUNKS * WORDS8;
    unsigned s0 = 0, s1 = 0, s2 = 0, s3 = 0;
#pragma unroll 4
    for (int c = 0; c < CHUNKS; ++c) {
        unsigned v = base[(size_t)c * WORDS8 + w];
        s0 += v & 0xFFu;
        s1 += (v >> 8) & 0xFFu;
        s2 += (v >> 16) & 0xFFu;
        s3 += v >> 24;
    }
    int ix = R0 + (w >> 8);                  // w / (RSZ * RSZ/4)
    int iy = R0 + ((w >> 3) & (RSZ - 1));
    int iz = R0 + ((w & (RSZ / 4 - 1)) << 2);
    float* __restrict__ outb = out + (size_t)b * BINS_PER_BATCH;
    int bin = (ix * GRIDSZ + iy) * GRIDSZ + iz;
    *reinterpret_cast<float4*>(&outb[bin]) =
        make_float4((float)s0, (float)s1, (float)s2, (float)s3);
}

// Fallback (ws too small): direct-atomic hist using finals from mm2.
__global__ void hist_kernel(const float* __restrict__ pts,
                            const float* __restrict__ finals,
                            float* __restrict__ out) {
    const int b = blockIdx.y;
    const float mn0 = finals[b * 8 + 0], mn1 = finals[b * 8 + 1], mn2 = finals[b * 8 + 2];
    const float d0  = finals[b * 8 + 3], d1  = finals[b * 8 + 4], d2  = finals[b * 8 + 5];

    const float4* __restrict__ p4 =
        reinterpret_cast<const float4*>(pts + (size_t)b * FLOATS_PER_BATCH);
    float* __restrict__ outb = out + (size_t)b * BINS_PER_BATCH;

    const int stride = gridDim.x * blockDim.x;
    for (int i = blockIdx.x * blockDim.x + threadIdx.x; i < NTRIP; i += stride) {
        float4 A = p4[3 * i + 0];
        float4 B = p4[3 * i + 1];
        float4 C = p4[3 * i + 2];
        float xs[4] = {A.x, A.w, B.z, C.y};
        float ys[4] = {A.y, B.x, B.w, C.z};
        float zs[4] = {A.z, B.y, C.x, C.w};
#pragma unroll
        for (int j = 0; j < 4; ++j) {
            bool ok; int ix, iy, iz;
            bin_point(xs[j], ys[j], zs[j], mn0, mn1, mn2, d0, d1, d2, ok, ix, iy, iz);
            if (ok) {
                int bin = (ix * GRIDSZ + iy) * GRIDSZ + iz;
                atomicAdd(&outb[bin], 1.0f);
            }
        }
    }
}

extern "C" void kernel_launch(void* const* d_in, const int* in_sizes, int n_in,
                              void* d_out, int out_size, void* d_ws, size_t ws_size,
                              hipStream_t stream) {
    const float* pts = (const float*)d_in[0];
    float* out = (float*)d_out;
    unsigned* ws = (unsigned*)d_ws;

    float* finals = (float*)(ws + FINAL_OFF);
    float* mm_partials = (float*)(ws + PART_OFF_U32);
    unsigned* hist_partials = ws + HIST_PART_OFF_U32;

    const size_t need = ((size_t)HIST_PART_OFF_U32 + (size_t)HBLOCKS * WORDS8) * 4;

    minmax_stage1<<<dim3(MMBLK, NBATCH), 256, 0, stream>>>(
        pts, mm_partials, (float4*)out);

    if (ws_size >= need) {
        hist_lds_kernel<<<HBLOCKS, HTHREADS, 0, stream>>>(
            pts, mm_partials, hist_partials, out);
        reduce_kernel<<<dim3(WORDS8 / 256, NBATCH), 256, 0, stream>>>(
            hist_partials, out);
    } else {
        minmax_stage2<<<NBATCH, MMBLK, 0, stream>>>(mm_partials, finals);
        hist_kernel<<<dim3(128, NBATCH), 256, 0, stream>>>(pts, finals, out);
    }
}